// Round 14
// baseline (125.032 us; speedup 1.0000x reference)
//
#include <hip/hip_runtime.h>
#include <hip/hip_bf16.h>

#define NN 50000
#define DD 64
#define EE 800000
#define NTILE 3125   // NN/16 row tiles (exact)
#define BCAP 64      // bucket capacity per node (P(deg>64) ~ 1e-14 for Poisson(16))
#define NR 196       // dst ranges: dst>>8, 49999>>8 = 195
#define NPB 512      // partition blocks / chunks
#define EPB 1563     // edges per chunk: 512*1563 = 800256 >= EE
#define RCAP 5120    // part[] slots per range; Poisson(4082), +16 sigma, gated
#define NLB 782      // linear blocks: ceil(NTILE/4)

typedef unsigned short u16;
typedef unsigned int u32;
typedef __attribute__((ext_vector_type(8))) short bf16x8;
typedef __attribute__((ext_vector_type(4))) float f32x4;

__device__ __forceinline__ float bf2f(u16 u) {
  u32 t = ((u32)u) << 16;
  return __builtin_bit_cast(float, t);
}
__device__ __forceinline__ u16 f2bf(float f) {
  u32 b = __builtin_bit_cast(u32, f);
  u32 r = (b + 0x7FFF + ((b >> 16) & 1)) >> 16;
  return (u16)r;
}

// ---------------------------------------------------------------------------
// Dispatch 1: fused partition + linear (r13 exact — validated).
//   blocks [0, NPB): partition chunk b into fixed-capacity range regions
//     part[r*RCAP ..]: pass 1 counts the chunk into LDS; 196 BATCHED device
//     atomics (one per range per block, issued 196-wide parallel — ~1
//     round-trip per block, NOT r5-r8's 800K serialized claims) reserve the
//     intra-region runs; pass 2 re-reads the chunk (L1-hot) and writes
//     packed u32 = src | (dst&255)<<16. Run writes are ~contiguous per
//     (block,range) — r12 lesson: never trade gaps for scattered traffic.
//   blocks [NPB, NPB+NLB): linear x = nf @ W.T + b_lin -> bf16 x16[N][64]
//     (verified; C/D map col=lane&15, row=(lane>>4)*4+reg [m89/m91];
//     interleaved rows — r1 planar split measured worse).
// range_cur[] must be zeroed by the preceding hipMemsetAsync (784 B).
// ---------------------------------------------------------------------------
__global__ __launch_bounds__(256) void fused_pl_kernel(
    const float* __restrict__ nf, const int* __restrict__ ei,
    const float* __restrict__ W, const float* __restrict__ b_lin,
    u16* __restrict__ x16, u32* __restrict__ part, int* __restrict__ range_cur) {
  __shared__ u16 Wsh[64 * 72];   // linear role
  __shared__ int lc[NR];         // partition role
  __shared__ int off_sh[NR];
  int b = blockIdx.x;
  int tid = threadIdx.x;

  if (b < NPB) {
    // ---- partition role ----
    if (tid < NR) lc[tid] = 0;
    __syncthreads();
    int ebeg = b * EPB;
    int eend = ebeg + EPB;
    if (eend > EE) eend = EE;
    // pass 1: count this chunk per range
#pragma unroll 1
    for (int i = ebeg + tid; i < eend; i += 256) {
      int2 v = *(const int2*)(ei + 2 * i);  // (src, dst)
      atomicAdd(&lc[v.y >> 8], 1);
    }
    __syncthreads();
    // batched reservation: one device atomic per range (196-wide parallel)
    if (tid < NR) {
      off_sh[tid] = atomicAdd(&range_cur[tid], lc[tid]);
      lc[tid] = 0;
    }
    __syncthreads();
    // pass 2: re-read chunk (L1-hot: 12.5 KB), claim local slot, write
#pragma unroll 1
    for (int i = ebeg + tid; i < eend; i += 256) {
      int2 v = *(const int2*)(ei + 2 * i);
      int r = v.y >> 8;
      int lp = atomicAdd(&lc[r], 1);
      int idx = off_sh[r] + lp;
      if (idx < RCAP)  // gated overflow drop (never triggers: +16 sigma)
        part[(size_t)r * RCAP + idx] = (u32)v.x | (((u32)v.y & 255u) << 16);
    }
    return;
  }

  // ---- linear role (verified, unchanged) ----
#pragma unroll
  for (int s = 0; s < 16; ++s) {
    int idx = s * 256 + tid;
    Wsh[(idx >> 6) * 72 + (idx & 63)] = f2bf(W[idx]);
  }
  __syncthreads();

  int wave = tid >> 6;
  int lane = tid & 63;
  int tile = (b - NPB) * 4 + wave;
  if (tile >= NTILE) return;  // after the barrier: safe

  int m = lane & 15;
  int quad = lane >> 4;
  int rowbase = tile * 16;

  bf16x8 bfrag[4][2];
#pragma unroll
  for (int c = 0; c < 4; ++c) {
#pragma unroll
    for (int ks = 0; ks < 2; ++ks) {
      const u16* p = &Wsh[(c * 16 + m) * 72 + ks * 32 + quad * 8];
      bfrag[c][ks] = *(const bf16x8*)p;
    }
  }

  bf16x8 afrag[2];
#pragma unroll
  for (int ks = 0; ks < 2; ++ks) {
    const float* p = nf + (rowbase + m) * DD + ks * 32 + quad * 8;
    float4 lo = *(const float4*)p;
    float4 hi = *(const float4*)(p + 4);
    bf16x8 a;
    a[0] = (short)f2bf(lo.x); a[1] = (short)f2bf(lo.y);
    a[2] = (short)f2bf(lo.z); a[3] = (short)f2bf(lo.w);
    a[4] = (short)f2bf(hi.x); a[5] = (short)f2bf(hi.y);
    a[6] = (short)f2bf(hi.z); a[7] = (short)f2bf(hi.w);
    afrag[ks] = a;
  }

  f32x4 acc[4];
#pragma unroll
  for (int c = 0; c < 4; ++c) {
    acc[c][0] = 0.0f; acc[c][1] = 0.0f; acc[c][2] = 0.0f; acc[c][3] = 0.0f;
  }
#pragma unroll
  for (int c = 0; c < 4; ++c) {
    acc[c] = __builtin_amdgcn_mfma_f32_16x16x32_bf16(afrag[0], bfrag[c][0], acc[c], 0, 0, 0);
    acc[c] = __builtin_amdgcn_mfma_f32_16x16x32_bf16(afrag[1], bfrag[c][1], acc[c], 0, 0, 0);
  }

#pragma unroll
  for (int c = 0; c < 4; ++c) {
    int gcol = c * 16 + m;
    float bl = b_lin[gcol];
#pragma unroll
    for (int r2 = 0; r2 < 4; ++r2) {
      int grow = rowbase + quad * 4 + r2;
      x16[grow * DD + gcol] = f2bf(acc[c][r2] + bl);
    }
  }
}

// ---------------------------------------------------------------------------
// gather chunk (verified r5 pattern): readlane broadcasts bucket entries to
// SGPR so row loads issue off scalar bases with high MLP. Entries >= win are
// garbage (uninitialized-LDS u16 -> idx < 65536 -> deref < 8.4 MB, inside
// x16+part region of d_ws); contributions cndmask-gated (NaN-safe select).
// ---------------------------------------------------------------------------
template <int BASE, int LEN>
__device__ __forceinline__ float chunkN(int my, int n,
                                        const u16* __restrict__ x16, int j) {
  float v[LEN];
#pragma unroll
  for (int k = 0; k < LEN; ++k) {
    int s = __builtin_amdgcn_readlane(my, BASE + k);
    v[k] = bf2f(x16[s * DD + j]);
  }
  float a = 0.0f;
#pragma unroll
  for (int k = 0; k < LEN; ++k) a += (BASE + k < n) ? v[k] : 0.0f;
  return a;
}

// ---------------------------------------------------------------------------
// Dispatch 2 (round-14 fix): fused bucket build + gather at QUARTER-range
// granularity. r13's defect: 196 blocks on 256 CUs = <=76% machine fill for
// a phase that r9 proved is random-read THROUGHPUT-bound -> gather ran
// ~29->~38 us. Now block (r,q) = blockIdx (784 blocks, 256 thr, 8.2 KB LDS
// -> ~3 blocks/CU, full machine): streams part[r] (4x re-read = +12.8 MB,
// L2/L3-served, coalesced — r12 lesson respected), claims only edges with
// dl>>6 == q into a 64-node LDS bucket, then 4 waves gather 16 nodes each.
// deg uses the TRUE count; junk bkt entries are u16 (deref stays in d_ws).
// ---------------------------------------------------------------------------
__global__ __launch_bounds__(256) void bucket_gather_kernel(
    const u32* __restrict__ part, const int* __restrict__ range_cur,
    const u16* __restrict__ x16, const float* __restrict__ bias,
    float* __restrict__ out) {
  __shared__ u16 bkt[64 * BCAP];  // 8 KB
  __shared__ int lcnt[64];
  int bg = blockIdx.x;            // [0, NR*4)
  int r = bg >> 2;
  int q = bg & 3;
  int tid = threadIdx.x;
  if (tid < 64) lcnt[tid] = 0;
  __syncthreads();

  int len = range_cur[r];
  if (len > RCAP) len = RCAP;
  const u32* pr = part + (size_t)r * RCAP;
#pragma unroll 1
  for (int i = tid; i < len; i += 256) {
    u32 e = pr[i];
    int dl = (int)((e >> 16) & 255u);
    if ((dl >> 6) == q) {
      int d6 = dl & 63;
      int lp = atomicAdd(&lcnt[d6], 1);
      if (lp < BCAP) bkt[d6 * BCAP + lp] = (u16)(e & 0xFFFFu);
    }
  }
  __syncthreads();

  int wave = tid >> 6;
  int j = tid & 63;
  float bj = bias[j];
  int nbase = (r << 8) + (q << 6);
#pragma unroll 1
  for (int it = 0; it < 16; ++it) {
    int nl = wave * 16 + it;
    int node = nbase + nl;
    if (node >= NN) break;  // only trims the last range (r=195)
    int deg = lcnt[nl];
    int win = deg < BCAP ? deg : BCAP;
    int my = (int)bkt[nl * BCAP + j];

    float acc = chunkN<0, 16>(my, win, x16, j);
    if (win > 16) acc += chunkN<16, 8>(my, win, x16, j);
    if (win > 24) acc += chunkN<24, 8>(my, win, x16, j);
    if (win > 32) acc += chunkN<32, 8>(my, win, x16, j);
    if (win > 40) acc += chunkN<40, 8>(my, win, x16, j);
    if (win > 48) acc += chunkN<48, 8>(my, win, x16, j);
    if (win > 56) acc += chunkN<56, 8>(my, win, x16, j);

    float inv = 1.0f / fmaxf((float)deg, 1.0f);
    float self = bf2f(x16[node * DD + j]);
    out[(size_t)node * DD + j] = fmaxf(fmaf(acc, inv, self + bj), 0.0f);
  }
}

extern "C" void kernel_launch(void* const* d_in, const int* in_sizes, int n_in,
                              void* d_out, int out_size, void* d_ws, size_t ws_size,
                              hipStream_t stream) {
  const float* nf    = (const float*)d_in[0];
  const int*   ei    = (const int*)d_in[1];
  const float* W     = (const float*)d_in[2];
  const float* b_lin = (const float*)d_in[3];
  const float* bias  = (const float*)d_in[4];
  float* out = (float*)d_out;

  // workspace layout (x16 MUST be at base: gather's garbage-index derefs
  // land in [0, 8.4 MB) = x16 + start of part, all inside d_ws)
  u16* x16       = (u16*)d_ws;                       // N*D bf16      (6.4 MB)
  u32* part      = (u32*)(x16 + (size_t)NN * DD);    // NR*RCAP u32   (4.0 MB)
  int* range_cur = (int*)(part + (size_t)NR * RCAP); // NR ints       (784 B)
  // total ~10.4 MB << ws_size

  // zero the per-range reservation counters (tiny, stream-ordered)
  hipMemsetAsync(range_cur, 0, NR * sizeof(int), stream);
  fused_pl_kernel<<<NPB + NLB, 256, 0, stream>>>(nf, ei, W, b_lin, x16, part, range_cur);
  bucket_gather_kernel<<<NR * 4, 256, 0, stream>>>(part, range_cur, x16, bias, out);
}

// Round 15
// 117.546 us; speedup vs baseline: 1.0637x; 1.0637x over previous
//
#include <hip/hip_runtime.h>
#include <hip/hip_bf16.h>

#define NN 50000
#define DD 64
#define EE 800000
#define NTILE 3125   // NN/16 row tiles (exact)
#define BCAP 64      // bucket capacity per node (P(deg>64) ~ 1e-14 for Poisson(16))
#define NR 196       // dst ranges: dst>>8, 49999>>8 = 195
#define NPB 512      // partition blocks / chunks
#define EPB 1563     // edges per chunk: 512*1563 = 800256 >= EE
#define NCB 512      // count blocks in kernel A (== NPB)
#define NLB 782      // linear blocks: ceil(NTILE/4)

typedef unsigned short u16;
typedef unsigned int u32;
typedef __attribute__((ext_vector_type(8))) short bf16x8;
typedef __attribute__((ext_vector_type(4))) float f32x4;

__device__ __forceinline__ float bf2f(u16 u) {
  u32 t = ((u32)u) << 16;
  return __builtin_bit_cast(float, t);
}
__device__ __forceinline__ u16 f2bf(float f) {
  u32 b = __builtin_bit_cast(u32, f);
  u32 r = (b + 0x7FFF + ((b >> 16) & 1)) >> 16;
  return (u16)r;
}

// chunk swizzle: consecutive edge-chunks handled by same-XCD blocks
// (round-robin block->XCD: b%8). Bijection on [0,512).
__device__ __forceinline__ int chunk_of(int b) { return (b & 7) * 64 + (b >> 3); }

// ---------------------------------------------------------------------------
// ROUND-11 EXACT (session best, 119.8 us). Rounds 12-14 each tried to
// compress this pipeline (cells / fixed-cap regions / fused bucket+gather /
// quarter-split) and all measured WORSE (128.9 / 122.7 / 125.0). Keep.
//
// Kernel A: linear || range-count.
// ---------------------------------------------------------------------------
__global__ __launch_bounds__(256) void fused_lc_kernel(
    const float* __restrict__ nf, const int* __restrict__ ei,
    const float* __restrict__ W, const float* __restrict__ b_lin,
    u16* __restrict__ x16, int* __restrict__ cnts) {
  int b = blockIdx.x;
  int tid = threadIdx.x;

  if (b < NCB) {
    // ---- count role ----
    __shared__ int csh[NR];
    int cb = chunk_of(b);
    int ebeg = cb * EPB;
    int eend = ebeg + EPB;
    if (eend > EE) eend = EE;
    if (tid < NR) csh[tid] = 0;
    __syncthreads();
#pragma unroll 1
    for (int i = ebeg + tid; i < eend; i += 256) {
      int2 v = *(const int2*)(ei + 2 * i);  // (src, dst)
      atomicAdd(&csh[v.y >> 8], 1);
    }
    __syncthreads();
    if (tid < NR) cnts[cb * NR + tid] = csh[tid];
    return;
  }

  // ---- linear role (verified; C/D map col=lane&15, row=(lane>>4)*4+reg
  // [m89/m91]; interleaved [N][64] rows — r1 planar split measured worse) ----
  __shared__ u16 Wsh[64 * 72];
#pragma unroll
  for (int s = 0; s < 16; ++s) {
    int idx = s * 256 + tid;
    Wsh[(idx >> 6) * 72 + (idx & 63)] = f2bf(W[idx]);
  }
  __syncthreads();

  int wave = tid >> 6;
  int lane = tid & 63;
  int tile = (b - NCB) * 4 + wave;
  if (tile >= NTILE) return;  // after the barrier: safe

  int m = lane & 15;
  int quad = lane >> 4;
  int rowbase = tile * 16;

  bf16x8 bfrag[4][2];
#pragma unroll
  for (int c = 0; c < 4; ++c) {
#pragma unroll
    for (int ks = 0; ks < 2; ++ks) {
      const u16* p = &Wsh[(c * 16 + m) * 72 + ks * 32 + quad * 8];
      bfrag[c][ks] = *(const bf16x8*)p;
    }
  }

  bf16x8 afrag[2];
#pragma unroll
  for (int ks = 0; ks < 2; ++ks) {
    const float* p = nf + (rowbase + m) * DD + ks * 32 + quad * 8;
    float4 lo = *(const float4*)p;
    float4 hi = *(const float4*)(p + 4);
    bf16x8 a;
    a[0] = (short)f2bf(lo.x); a[1] = (short)f2bf(lo.y);
    a[2] = (short)f2bf(lo.z); a[3] = (short)f2bf(lo.w);
    a[4] = (short)f2bf(hi.x); a[5] = (short)f2bf(hi.y);
    a[6] = (short)f2bf(hi.z); a[7] = (short)f2bf(hi.w);
    afrag[ks] = a;
  }

  f32x4 acc[4];
#pragma unroll
  for (int c = 0; c < 4; ++c) {
    acc[c][0] = 0.0f; acc[c][1] = 0.0f; acc[c][2] = 0.0f; acc[c][3] = 0.0f;
  }
#pragma unroll
  for (int c = 0; c < 4; ++c) {
    acc[c] = __builtin_amdgcn_mfma_f32_16x16x32_bf16(afrag[0], bfrag[c][0], acc[c], 0, 0, 0);
    acc[c] = __builtin_amdgcn_mfma_f32_16x16x32_bf16(afrag[1], bfrag[c][1], acc[c], 0, 0, 0);
  }

#pragma unroll
  for (int c = 0; c < 4; ++c) {
    int gcol = c * 16 + m;
    float bl = b_lin[gcol];
#pragma unroll
    for (int r2 = 0; r2 < 4; ++r2) {
      int grow = rowbase + quad * 4 + r2;
      x16[grow * DD + gcol] = f2bf(acc[c][r2] + bl);
    }
  }
}

// ---------------------------------------------------------------------------
// Kernel B: PARALLEL per-range scan (r10's 1-block serial scan was 124.8 us;
// this is ~4 us). One block per range r; 2 chunk counts per thread,
// pair-scan + Hillis-Steele over 256 pair-sums in LDS. Writes offs[chunk][r]
// (LOCAL prefix) and range_tot[r]; downstream kernels recover range_base by
// redundantly scanning range_tot[196] in LDS.
// ---------------------------------------------------------------------------
__global__ __launch_bounds__(256) void scanA_kernel(
    const int* __restrict__ cnts, int* __restrict__ offs,
    int* __restrict__ range_tot) {
  __shared__ int sp[256];
  int r = blockIdx.x;  // [0, NR)
  int t = threadIdx.x;
  int c0 = cnts[(2 * t) * NR + r];
  int c1 = cnts[(2 * t + 1) * NR + r];
  int p = c0 + c1;
  sp[t] = p;
  __syncthreads();
#pragma unroll
  for (int o = 1; o < 256; o <<= 1) {
    int u = (t >= o) ? sp[t - o] : 0;
    __syncthreads();
    sp[t] += u;
    __syncthreads();
  }
  int base = sp[t] - p;  // exclusive over pairs (chunk order = natural)
  offs[(2 * t) * NR + r] = base;
  offs[(2 * t + 1) * NR + r] = base + c0;
  if (t == 255) range_tot[r] = sp[255];
}

// ---------------------------------------------------------------------------
// Kernel C: partition. Block b re-reads chunk cb's edges, claims local slots
// via LDS atomics (block-exclusive, no global atomics), writes packed edge
// u32 = src | (dst&255)<<16 into its pre-assigned region of part[].
// ---------------------------------------------------------------------------
__global__ __launch_bounds__(256) void part_kernel(
    const int* __restrict__ ei, const int* __restrict__ offs,
    const int* __restrict__ range_tot, u32* __restrict__ part) {
  __shared__ int sp[256];
  __shared__ int off_sh[NR];
  __shared__ int lcnt[NR];
  int b = blockIdx.x;
  int tid = threadIdx.x;
  int cb = chunk_of(b);

  sp[tid] = (tid < NR) ? range_tot[tid] : 0;
  __syncthreads();
#pragma unroll
  for (int o = 1; o < 256; o <<= 1) {
    int u = (tid >= o) ? sp[tid - o] : 0;
    __syncthreads();
    sp[tid] += u;
    __syncthreads();
  }
  if (tid < NR) {
    int base = (tid > 0) ? sp[tid - 1] : 0;  // exclusive range base
    off_sh[tid] = base + offs[cb * NR + tid];
    lcnt[tid] = 0;
  }
  __syncthreads();

  int ebeg = cb * EPB;
  int eend = ebeg + EPB;
  if (eend > EE) eend = EE;
#pragma unroll 1
  for (int i = ebeg + tid; i < eend; i += 256) {
    int2 v = *(const int2*)(ei + 2 * i);  // (src, dst)
    int r = v.y >> 8;
    int lp = atomicAdd(&lcnt[r], 1);
    part[off_sh[r] + lp] = (u32)v.x | (((u32)v.y & 255u) << 16);
  }
}

// ---------------------------------------------------------------------------
// Kernel D1: bucket build, one block per range (256 nodes). All claims are
// LDS atomics; bucket + cnt lines written ONCE, coalesced, by exactly one
// block (r6: shared bucket lines across XCDs cost 51.2 MB = 50000*128*8 of
// writeback). bkt[] junk beyond lcnt is u16 -> gather's garbage derefs stay
// in [0, 12.8 MB) of d_ws.
// ---------------------------------------------------------------------------
__global__ __launch_bounds__(256) void bucket_kernel(
    const u32* __restrict__ part, const int* __restrict__ range_tot,
    u16* __restrict__ bucket, int* __restrict__ cnt) {
  __shared__ int sp[256];
  __shared__ u16 bkt[256 * BCAP];  // 32 KB
  __shared__ int lcnt[256];
  int r = blockIdx.x;  // [0, NR)
  int tid = threadIdx.x;

  sp[tid] = (tid < NR) ? range_tot[tid] : 0;
  lcnt[tid] = 0;
  __syncthreads();
#pragma unroll
  for (int o = 1; o < 256; o <<= 1) {
    int u = (tid >= o) ? sp[tid - o] : 0;
    __syncthreads();
    sp[tid] += u;
    __syncthreads();
  }
  int beg = (r > 0) ? sp[r - 1] : 0;
  int end = sp[r];

#pragma unroll 1
  for (int i = beg + tid; i < end; i += 256) {
    u32 e = part[i];
    int dl = (int)(e >> 16);       // bits 16-23: dst & 255
    int lp = atomicAdd(&lcnt[dl], 1);
    if (lp < BCAP) bkt[dl * BCAP + lp] = (u16)(e & 0xFFFFu);
  }
  __syncthreads();
  int nb = r << 8;
  if (nb + tid < NN) cnt[nb + tid] = lcnt[tid];
  const u32* bs = (const u32*)bkt;
  u32* bg = (u32*)bucket;
#pragma unroll 1
  for (int k = tid; k < 256 * (BCAP / 2); k += 256) {
    int dl = k >> 5;  // 32 u32 per node
    if (nb + dl < NN) bg[(size_t)(nb + dl) * (BCAP / 2) + (k & 31)] = bs[k];
  }
}

// ---------------------------------------------------------------------------
// gather (round-5 exact; r9 proved L2/L3 random-read throughput-bound ->
// structural floor ~29 us; r13/r14 LDS-fused variants measured worse).
// One wave per node; 128 B bucket load + readlane broadcast -> SGPR-based
// row loads, high MLP. Lanes >= deg hold garbage u16 indices; reads stay
// inside d_ws; contributions cndmask-gated (NaN-safe select).
// ---------------------------------------------------------------------------
template <int BASE, int LEN>
__device__ __forceinline__ float chunkN(int my, int n,
                                        const u16* __restrict__ x16, int j) {
  float v[LEN];
#pragma unroll
  for (int k = 0; k < LEN; ++k) {
    int s = __builtin_amdgcn_readlane(my, BASE + k);
    v[k] = bf2f(x16[s * DD + j]);
  }
  float a = 0.0f;
#pragma unroll
  for (int k = 0; k < LEN; ++k) a += (BASE + k < n) ? v[k] : 0.0f;
  return a;
}

__global__ __launch_bounds__(256) void gather_kernel(
    const u16* __restrict__ x16, const u16* __restrict__ bucket,
    const int* __restrict__ cnt, const float* __restrict__ bias,
    float* __restrict__ out) {
  int i = blockIdx.x * 4 + (threadIdx.x >> 6);  // grid exact: NN/4 blocks
  int j = threadIdx.x & 63;
  int deg = cnt[i];
  int win = deg < BCAP ? deg : BCAP;
  int my = (int)bucket[i * BCAP + j];

  float acc = chunkN<0, 16>(my, win, x16, j);
  if (win > 16) acc += chunkN<16, 8>(my, win, x16, j);
  if (win > 24) acc += chunkN<24, 8>(my, win, x16, j);
  if (win > 32) acc += chunkN<32, 8>(my, win, x16, j);
  if (win > 40) acc += chunkN<40, 8>(my, win, x16, j);
  if (win > 48) acc += chunkN<48, 8>(my, win, x16, j);
  if (win > 56) acc += chunkN<56, 8>(my, win, x16, j);

  float inv = 1.0f / fmaxf((float)deg, 1.0f);
  float self = bf2f(x16[i * DD + j]);
  out[i * DD + j] = fmaxf(fmaf(acc, inv, self + bias[j]), 0.0f);
}

extern "C" void kernel_launch(void* const* d_in, const int* in_sizes, int n_in,
                              void* d_out, int out_size, void* d_ws, size_t ws_size,
                              hipStream_t stream) {
  const float* nf    = (const float*)d_in[0];
  const int*   ei    = (const int*)d_in[1];
  const float* W     = (const float*)d_in[2];
  const float* b_lin = (const float*)d_in[3];
  const float* bias  = (const float*)d_in[4];
  float* out = (float*)d_out;

  // workspace layout (x16 then bucket MUST be first 12.8 MB: gather's
  // garbage-index derefs land in [0, 8.4 MB))
  u16* x16       = (u16*)d_ws;                         // N*D bf16   (6.4 MB)
  u16* bucket    = x16 + (size_t)NN * DD;              // N*BCAP u16 (6.4 MB)
  int* cnt       = (int*)(bucket + (size_t)NN * BCAP); // N ints     (200 KB)
  u32* part      = (u32*)(cnt + NN);                   // E u32      (3.2 MB)
  int* cnts      = (int*)(part + EE);                  // NPB*NR     (401 KB)
  int* offs      = cnts + NPB * NR;                    // NPB*NR     (401 KB)
  int* range_tot = offs + NPB * NR;                    // NR ints
  // total ~17 MB << ws_size; no memset needed (all regions fully written)

  fused_lc_kernel<<<NCB + NLB, 256, 0, stream>>>(nf, ei, W, b_lin, x16, cnts);
  scanA_kernel<<<NR, 256, 0, stream>>>(cnts, offs, range_tot);
  part_kernel<<<NPB, 256, 0, stream>>>(ei, offs, range_tot, part);
  bucket_kernel<<<NR, 256, 0, stream>>>(part, range_tot, bucket, cnt);
  gather_kernel<<<NN / 4, 256, 0, stream>>>(x16, bucket, cnt, bias, out);
}